// Round 5
// baseline (266.690 us; speedup 1.0000x reference)
//
#include <hip/hip_runtime.h>
#include <hip/hip_bf16.h>

// INRformer forward, MI355X gfx950. Inputs f32, labels i32, output f32 (4096x1).
// B=4096, D=128, H=4, HD=32, NC=10. Internal activations bf16 for MFMA.
// Round 5: round-4 structure with CORRECTED workspace offsets (r4 bug: wsb
// extent computed in elements, xb overlapped mlp weights -> garbage weights).

typedef __bf16 bf16_t;
typedef __bf16 bf16x8 __attribute__((ext_vector_type(8)));
typedef __bf16 bf16x4 __attribute__((ext_vector_type(4)));
typedef __bf16 bf16x2 __attribute__((ext_vector_type(2)));
typedef float  f32x4  __attribute__((ext_vector_type(4)));
typedef float  f32x2  __attribute__((ext_vector_type(2)));

__device__ __forceinline__ f32x4 mfma16(bf16x8 a, bf16x8 b, f32x4 c) {
  return __builtin_amdgcn_mfma_f32_16x16x32_bf16(a, b, c, 0, 0, 0);
}

// --------------------------------------- init: embed+PE | weight cvt | catab
// blocks [0,2048): embed; [2048,2368): cvtw; 2368: catab (10-row ca table).
__global__ __launch_bounds__(256) void k_init(const float* __restrict__ coords,
                                              const float* __restrict__ ce_w,
                                              const float* __restrict__ ce_b,
                                              float* __restrict__ xf,
                                              bf16_t* __restrict__ xb,
                                              const float* __restrict__ s0,
                                              const float* __restrict__ s1,
                                              const float* __restrict__ s2,
                                              const float* __restrict__ s3,
                                              const float* __restrict__ s4,
                                              const float* __restrict__ s5,
                                              bf16_t* __restrict__ wdst,
                                              const float* __restrict__ emb,
                                              const float* __restrict__ wvp,
                                              const float* __restrict__ bvp,
                                              const float* __restrict__ cow,
                                              const float* __restrict__ cob,
                                              float* __restrict__ tab) {
  const int bid = blockIdx.x;
  const int tid = threadIdx.x;
  if (bid < 2048) {  // ---- embed + positional encoding
    int row = bid * 2 + (tid >> 7);
    int d   = tid & 127;
    float c0 = coords[row * 2 + 0];
    float c1 = coords[row * 2 + 1];
    int   j  = d >> 1;
    float inv = exp2f(-0.20762050593045953f * (float)j);  // 10000^(-2j/128)
    float pe  = (d & 1) ? cosf(c1 * inv) : sinf(c0 * inv);
    float x = c0 * ce_w[2 * d] + c1 * ce_w[2 * d + 1] + ce_b[d] + pe;
    xf[(size_t)row * 128 + d] = x;
    xb[(size_t)row * 128 + d] = (bf16_t)x;
  } else if (bid < 2368) {  // ---- weight f32->bf16 (4 elems/thread)
    int i = (bid - 2048) * 256 + tid;  // < 81920
    const float* src; int off;
    if      (i < 12288) { src = s0; off = i; }
    else if (i < 16384) { src = s1; off = i - 12288; }
    else if (i < 32768) { src = s2; off = i - 16384; }
    else if (i < 49152) { src = s3; off = i - 32768; }
    else if (i < 65536) { src = s4; off = i - 49152; }
    else                { src = s5; off = i - 65536; }
    f32x4 v = *(const f32x4*)(src + (size_t)off * 4);
    bf16x4 o = {(bf16_t)v[0], (bf16_t)v[1], (bf16_t)v[2], (bf16_t)v[3]};
    *(bf16x4*)(wdst + (size_t)i * 4) = o;
  } else {  // ---- ca table: tab[c] = (emb[c]@wv^T+bv)@ca_out^T+ca_out_b
    __shared__ float embs[10][128];
    __shared__ float t1[10][128];
    for (int i = tid; i < 1280; i += 256) embs[i >> 7][i & 127] = emb[i];
    __syncthreads();
    for (int o = tid; o < 1280; o += 256) {
      int c = o >> 7, n = o & 127;
      float acc = bvp[n];
      const float* wr = wvp + n * 128;
      for (int k2 = 0; k2 < 128; k2++) acc += embs[c][k2] * wr[k2];
      t1[c][n] = acc;
    }
    __syncthreads();
    for (int o = tid; o < 1280; o += 256) {
      int c = o >> 7, dd = o & 127;
      float acc = cob[dd];
      const float* wr = cow + dd * 128;
      for (int n = 0; n < 128; n++) acc += t1[c][n] * wr[n];
      tab[o] = acc;
    }
  }
}

// ------------------------------------------------------- generic MFMA GEMM
// out[M x N] = epi(X[M x K] @ W[N x K]^T + bias). Operand-swapped: A=W rows
// (m=out col), B=X rows (n=out row) -> lane's f32x4 = 4 consecutive out cols.
// 64x64 tile/block, 4 waves 2x2. vTout (qkv only): V cols also transposed.
enum { EPI_BF16 = 1, EPI_GELU_BF16 = 2 };

template <int K, int EPI>
__global__ __launch_bounds__(256) void k_gemm(const bf16_t* __restrict__ X,
                                              const bf16_t* __restrict__ Wb,
                                              const float* __restrict__ bias,
                                              bf16_t* __restrict__ outB,
                                              bf16_t* __restrict__ vTout,
                                              int N) {
  const int tid  = threadIdx.x;
  const int lane = tid & 63;
  const int wv   = tid >> 6;
  const int l15  = lane & 15;
  const int quad = lane >> 4;
  const int xbase = blockIdx.x * 64 + (wv >> 1) * 32;  // output rows
  const int wbase = blockIdx.y * 64 + (wv & 1) * 32;   // output cols

  const bf16_t* wr0 = Wb + (size_t)(wbase + l15) * K + quad * 8;
  const bf16_t* xr0 = X  + (size_t)(xbase + l15) * K + quad * 8;

  f32x4 acc[2][2];  // [i: col tile][t: row tile]
  const f32x4 zero4 = {0.f, 0.f, 0.f, 0.f};
  for (int i = 0; i < 2; i++)
    for (int t = 0; t < 2; t++) acc[i][t] = zero4;

#pragma unroll 4
  for (int kk = 0; kk < K; kk += 32) {
    bf16x8 a0 = *(const bf16x8*)(wr0 + kk);
    bf16x8 a1 = *(const bf16x8*)(wr0 + 16 * K + kk);
    bf16x8 b0 = *(const bf16x8*)(xr0 + kk);
    bf16x8 b1 = *(const bf16x8*)(xr0 + 16 * K + kk);
    acc[0][0] = mfma16(a0, b0, acc[0][0]);
    acc[0][1] = mfma16(a0, b1, acc[0][1]);
    acc[1][0] = mfma16(a1, b0, acc[1][0]);
    acc[1][1] = mfma16(a1, b1, acc[1][1]);
  }

  f32x4 bv[2];
  bv[0] = *(const f32x4*)(bias + wbase + quad * 4);
  bv[1] = *(const f32x4*)(bias + wbase + 16 + quad * 4);
#pragma unroll
  for (int t = 0; t < 2; t++) {
    int row = xbase + t * 16 + l15;
#pragma unroll
    for (int i = 0; i < 2; i++) {
      int col0 = wbase + i * 16 + quad * 4;
      f32x4 v = acc[i][t] + bv[i];
      if (EPI == EPI_GELU_BF16) {
#pragma unroll
        for (int r = 0; r < 4; r++)
          v[r] = 0.5f * v[r] * (1.0f + erff(v[r] * 0.70710678118654752f));
      }
      bf16x4 o = {(bf16_t)v[0], (bf16_t)v[1], (bf16_t)v[2], (bf16_t)v[3]};
      *(bf16x4*)(outB + (size_t)row * N + col0) = o;
      if (vTout && col0 >= 256) {  // V block: also store transposed
#pragma unroll
        for (int r = 0; r < 4; r++)
          vTout[(size_t)(col0 - 256 + r) * 4096 + row] = (bf16_t)v[r];
      }
    }
  }
}

// --------------------------------------- GEMM (N=128) + residual + LN fused
// One block = 64 rows x all 128 cols. 4 waves: rhalf=wv>>1 (32 rows),
// chalf=wv&1 (64 cols), each wave 2x4 of 16x16 tiles. LN over full rows via
// quad-shuffles + 1KB LDS cross-wave-half reduce.
// MODE 0: +resid, LN(g1,b1) -> xf,xb.
// MODE 1: +resid, LN(g1,b1), +tab[labels], LN(g2,b2) -> xf,xb.
// MODE 2: +resid, LN(g1,b1), dot fin_w + fin_b -> sigmoid -> out.
template <int K, int MODE>
__global__ __launch_bounds__(256) void k_gemmln(const bf16_t* __restrict__ X,
                                                const bf16_t* __restrict__ Wb,
                                                const float* __restrict__ bias,
                                                const float* __restrict__ resid,
                                                const float* __restrict__ g1,
                                                const float* __restrict__ b1,
                                                const int* __restrict__ labels,
                                                const float* __restrict__ tab,
                                                const float* __restrict__ g2,
                                                const float* __restrict__ b2,
                                                const float* __restrict__ fw,
                                                const float* __restrict__ fb,
                                                float* __restrict__ xf_out,
                                                bf16_t* __restrict__ xb_out,
                                                float* __restrict__ out) {
  __shared__ float red[2][64][2];  // [metric][row-in-block][col-half]

  const int tid  = threadIdx.x;
  const int lane = tid & 63;
  const int wv   = tid >> 6;
  const int l15  = lane & 15;
  const int quad = lane >> 4;
  const int rhalf = wv >> 1, chalf = wv & 1;
  const int rb = blockIdx.x * 64 + rhalf * 32;
  const int cb = chalf * 64;

  const bf16_t* xr0 = X  + (size_t)(rb + l15) * K + quad * 8;
  const bf16_t* wr0 = Wb + (size_t)(cb + l15) * K + quad * 8;

  f32x4 acc[2][4];  // [t: row tile][i: col tile]
  const f32x4 zero4 = {0.f, 0.f, 0.f, 0.f};
  for (int t = 0; t < 2; t++)
    for (int i = 0; i < 4; i++) acc[t][i] = zero4;

#pragma unroll 4
  for (int kk = 0; kk < K; kk += 32) {
    bf16x8 b0 = *(const bf16x8*)(xr0 + kk);
    bf16x8 b1 = *(const bf16x8*)(xr0 + 16 * K + kk);
#pragma unroll
    for (int i = 0; i < 4; i++) {
      bf16x8 a = *(const bf16x8*)(wr0 + (size_t)i * 16 * K + kk);
      acc[0][i] = mfma16(a, b0, acc[0][i]);
      acc[1][i] = mfma16(a, b1, acc[1][i]);
    }
  }

  // bias + residual; per-row sums
  f32x4 v[2][4];
  float s[2] = {0.f, 0.f}, sq[2] = {0.f, 0.f};
#pragma unroll
  for (int t = 0; t < 2; t++) {
    int row = rb + t * 16 + l15;
#pragma unroll
    for (int i = 0; i < 4; i++) {
      int c = cb + i * 16 + quad * 4;
      f32x4 vv = acc[t][i] + *(const f32x4*)(bias + c)
               + *(const f32x4*)(resid + (size_t)row * 128 + c);
      v[t][i] = vv;
      s[t]  += (vv[0] + vv[1]) + (vv[2] + vv[3]);
      sq[t] += (vv[0] * vv[0] + vv[1] * vv[1]) + (vv[2] * vv[2] + vv[3] * vv[3]);
    }
  }
#pragma unroll
  for (int t = 0; t < 2; t++) {
    s[t]  += __shfl_xor(s[t], 16, 64);  s[t]  += __shfl_xor(s[t], 32, 64);
    sq[t] += __shfl_xor(sq[t], 16, 64); sq[t] += __shfl_xor(sq[t], 32, 64);
    if (quad == 0) {
      red[0][rhalf * 32 + t * 16 + l15][chalf] = s[t];
      red[1][rhalf * 32 + t * 16 + l15][chalf] = sq[t];
    }
  }
  __syncthreads();
  float mean[2], rstd[2];
#pragma unroll
  for (int t = 0; t < 2; t++) {
    int rl = rhalf * 32 + t * 16 + l15;
    float S  = red[0][rl][0] + red[0][rl][1];
    float SQ = red[1][rl][0] + red[1][rl][1];
    mean[t] = S * (1.0f / 128.0f);
    rstd[t] = rsqrtf(SQ * (1.0f / 128.0f) - mean[t] * mean[t] + 1e-5f);
  }

  f32x4 g4[4], b4[4];
#pragma unroll
  for (int i = 0; i < 4; i++) {
    int c = cb + i * 16 + quad * 4;
    g4[i] = *(const f32x4*)(g1 + c);
    b4[i] = *(const f32x4*)(b1 + c);
  }

  if (MODE == 0) {
#pragma unroll
    for (int t = 0; t < 2; t++) {
      int row = rb + t * 16 + l15;
#pragma unroll
      for (int i = 0; i < 4; i++) {
        int c = cb + i * 16 + quad * 4;
        f32x4 y = (v[t][i] - mean[t]) * rstd[t] * g4[i] + b4[i];
        *(f32x4*)(xf_out + (size_t)row * 128 + c) = y;
        bf16x4 o = {(bf16_t)y[0], (bf16_t)y[1], (bf16_t)y[2], (bf16_t)y[3]};
        *(bf16x4*)(xb_out + (size_t)row * 128 + c) = o;
      }
    }
  } else if (MODE == 1) {
    // second LN with gathered class-table branch
    int lab[2];
    float s2v[2] = {0.f, 0.f}, sq2[2] = {0.f, 0.f};
#pragma unroll
    for (int t = 0; t < 2; t++) {
      lab[t] = labels[rb + t * 16 + l15];
#pragma unroll
      for (int i = 0; i < 4; i++) {
        int c = cb + i * 16 + quad * 4;
        f32x4 y = (v[t][i] - mean[t]) * rstd[t] * g4[i] + b4[i];
        y = y + *(const f32x4*)(tab + (size_t)lab[t] * 128 + c);
        v[t][i] = y;
        s2v[t] += (y[0] + y[1]) + (y[2] + y[3]);
        sq2[t] += (y[0] * y[0] + y[1] * y[1]) + (y[2] * y[2] + y[3] * y[3]);
      }
    }
    __syncthreads();  // all first-round red reads done
#pragma unroll
    for (int t = 0; t < 2; t++) {
      s2v[t] += __shfl_xor(s2v[t], 16, 64); s2v[t] += __shfl_xor(s2v[t], 32, 64);
      sq2[t] += __shfl_xor(sq2[t], 16, 64); sq2[t] += __shfl_xor(sq2[t], 32, 64);
      if (quad == 0) {
        red[0][rhalf * 32 + t * 16 + l15][chalf] = s2v[t];
        red[1][rhalf * 32 + t * 16 + l15][chalf] = sq2[t];
      }
    }
    __syncthreads();
#pragma unroll
    for (int t = 0; t < 2; t++) {
      int rl = rhalf * 32 + t * 16 + l15;
      float S  = red[0][rl][0] + red[0][rl][1];
      float SQ = red[1][rl][0] + red[1][rl][1];
      mean[t] = S * (1.0f / 128.0f);
      rstd[t] = rsqrtf(SQ * (1.0f / 128.0f) - mean[t] * mean[t] + 1e-5f);
    }
#pragma unroll
    for (int t = 0; t < 2; t++) {
      int row = rb + t * 16 + l15;
#pragma unroll
      for (int i = 0; i < 4; i++) {
        int c = cb + i * 16 + quad * 4;
        f32x4 y = (v[t][i] - mean[t]) * rstd[t] * (*(const f32x4*)(g2 + c))
                + *(const f32x4*)(b2 + c);
        *(f32x4*)(xf_out + (size_t)row * 128 + c) = y;
        bf16x4 o = {(bf16_t)y[0], (bf16_t)y[1], (bf16_t)y[2], (bf16_t)y[3]};
        *(bf16x4*)(xb_out + (size_t)row * 128 + c) = o;
      }
    }
  } else {  // MODE 2: LN -> fin dot -> sigmoid
    float dot[2] = {0.f, 0.f};
#pragma unroll
    for (int t = 0; t < 2; t++) {
#pragma unroll
      for (int i = 0; i < 4; i++) {
        int c = cb + i * 16 + quad * 4;
        f32x4 y = (v[t][i] - mean[t]) * rstd[t] * g4[i] + b4[i];
        f32x4 fw4 = *(const f32x4*)(fw + c);
        dot[t] += (y[0] * fw4[0] + y[1] * fw4[1]) + (y[2] * fw4[2] + y[3] * fw4[3]);
      }
    }
    __syncthreads();
#pragma unroll
    for (int t = 0; t < 2; t++) {
      dot[t] += __shfl_xor(dot[t], 16, 64); dot[t] += __shfl_xor(dot[t], 32, 64);
      if (quad == 0) red[0][rhalf * 32 + t * 16 + l15][chalf] = dot[t];
    }
    __syncthreads();
    if (chalf == 0 && quad == 0) {
      float fbv = fb[0];
#pragma unroll
      for (int t = 0; t < 2; t++) {
        int rl = rhalf * 32 + t * 16 + l15;
        float logit = red[0][rl][0] + red[0][rl][1] + fbv;
        out[blockIdx.x * 64 + rl] = 1.0f / (1.0f + expf(-logit));
      }
    }
  }
}

// ----------------------------------------- flash-decoding attention partial
// m=0 softmax (scores tiny) -> no barriers, no online max. One wave =
// (head, 16-query tile, 512-key split); 8192 wave-tasks = 8 waves/SIMD.
// Partials: O bf16 (precision slack ~3e-5 at attn out), l f32.
__global__ __launch_bounds__(256) void k_attn(const bf16_t* __restrict__ qkv,
                                              const bf16_t* __restrict__ vT,
                                              bf16_t* __restrict__ opart,
                                              float* __restrict__ lpart) {
  __shared__ bf16_t pt[4][16][72];  // per-wave P round-trip

  const int tid  = threadIdx.x;
  const int lane = tid & 63;
  const int wv   = tid >> 6;
  const int l15  = lane & 15;
  const int quad = lane >> 4;
  const int task = blockIdx.x * 4 + wv;  // 0..8191
  const int h    = task & 3;
  const int ks   = (task >> 2) & 7;
  const int qt   = task >> 5;
  const int q0   = qt * 16;
  const int kb   = ks * 512;

  bf16x8 qf;  // Q A-frag, prescaled by 1/sqrt(32)
  {
    bf16x8 qraw = *(const bf16x8*)(qkv + (size_t)(q0 + l15) * 384 + h * 32 + quad * 8);
#pragma unroll
    for (int j = 0; j < 8; j++)
      qf[j] = (bf16_t)((float)qraw[j] * 0.17677669529663687f);
  }

  const f32x4 zero4 = {0.f, 0.f, 0.f, 0.f};
  f32x4 o0 = zero4, o1 = zero4;   // O[q=quad*4+r][d=l15 / 16+l15]
  f32x4 lacc = zero4;

  const bf16_t* kbase = qkv + 128 + h * 32 + quad * 8 + (size_t)l15 * 384;
  const bf16_t* vbase = vT + (size_t)(h * 32 + l15) * 4096 + quad * 8;

  for (int kk = 0; kk < 512; kk += 64) {
    const bf16_t* kp = kbase + (size_t)(kb + kk) * 384;
    bf16x8 kf0 = *(const bf16x8*)(kp);
    bf16x8 kf1 = *(const bf16x8*)(kp + 16 * 384);
    bf16x8 kf2 = *(const bf16x8*)(kp + 32 * 384);
    bf16x8 kf3 = *(const bf16x8*)(kp + 48 * 384);
    f32x4 s0 = mfma16(qf, kf0, zero4);
    f32x4 s1 = mfma16(qf, kf1, zero4);
    f32x4 s2 = mfma16(qf, kf2, zero4);
    f32x4 s3 = mfma16(qf, kf3, zero4);

#pragma unroll
    for (int r = 0; r < 4; r++) {
      float p0 = __expf(s0[r]);
      float p1 = __expf(s1[r]);
      float p2 = __expf(s2[r]);
      float p3 = __expf(s3[r]);
      lacc[r] += (p0 + p1) + (p2 + p3);
      pt[wv][quad * 4 + r][l15]      = (bf16_t)p0;
      pt[wv][quad * 4 + r][l15 + 16] = (bf16_t)p1;
      pt[wv][quad * 4 + r][l15 + 32] = (bf16_t)p2;
      pt[wv][quad * 4 + r][l15 + 48] = (bf16_t)p3;
    }
    bf16x8 pa0 = *(const bf16x8*)&pt[wv][l15][quad * 8];
    bf16x8 pa1 = *(const bf16x8*)&pt[wv][l15][32 + quad * 8];

    const bf16_t* vp = vbase + kb + kk;
    bf16x8 v00 = *(const bf16x8*)(vp);
    bf16x8 v01 = *(const bf16x8*)(vp + 16 * 4096);
    bf16x8 v10 = *(const bf16x8*)(vp + 32);
    bf16x8 v11 = *(const bf16x8*)(vp + 16 * 4096 + 32);
    o0 = mfma16(pa0, v00, o0);
    o0 = mfma16(pa1, v10, o0);
    o1 = mfma16(pa0, v01, o1);
    o1 = mfma16(pa1, v11, o1);
  }

#pragma unroll
  for (int r = 0; r < 4; r++) {
    float lv = lacc[r];
    lv += __shfl_xor(lv, 1, 16);
    lv += __shfl_xor(lv, 2, 16);
    lv += __shfl_xor(lv, 4, 16);
    lv += __shfl_xor(lv, 8, 16);
    lacc[r] = lv;
  }

  size_t ob = ((size_t)task * 16 + quad * 4) * 32;
#pragma unroll
  for (int r = 0; r < 4; r++) {
    opart[ob + r * 32 + l15]      = (bf16_t)o0[r];
    opart[ob + r * 32 + 16 + l15] = (bf16_t)o1[r];
    if (l15 == 0) lpart[task * 16 + quad * 4 + r] = lacc[r];
  }
}

// ------------------------------------------------ combine ksplit partials
__global__ __launch_bounds__(256) void k_attn_fin(const bf16_t* __restrict__ opart,
                                                  const float* __restrict__ lpart,
                                                  bf16_t* __restrict__ attnb) {
  int idx = blockIdx.x * 256 + threadIdx.x;  // ((h*4096+q)*32+d), < 524288
  int d  = idx & 31;
  int q  = (idx >> 5) & 4095;
  int h  = idx >> 17;
  int qt = q >> 4, ql = q & 15;
  float O = 0.f, L = 0.f;
#pragma unroll
  for (int ks = 0; ks < 8; ks++) {
    int t = qt * 32 + ks * 4 + h;
    O += (float)opart[((size_t)t * 16 + ql) * 32 + d];
    L += lpart[t * 16 + ql];
  }
  attnb[(size_t)q * 128 + h * 32 + d] = (bf16_t)(O / L);
}

// --------------------------------------------------------------------------
extern "C" void kernel_launch(void* const* d_in, const int* in_sizes, int n_in,
                              void* d_out, int out_size, void* d_ws, size_t ws_size,
                              hipStream_t stream) {
  const float* coords  = (const float*)d_in[0];
  const int*   labels  = (const int*)d_in[1];
  const float* ce_w    = (const float*)d_in[2];
  const float* ce_b    = (const float*)d_in[3];
  const float* emb     = (const float*)d_in[4];
  const float* sa_in_w = (const float*)d_in[5];
  const float* sa_in_b = (const float*)d_in[6];
  const float* sa_out_w= (const float*)d_in[7];
  const float* sa_out_b= (const float*)d_in[8];
  const float* n1_g    = (const float*)d_in[9];
  const float* n1_b    = (const float*)d_in[10];
  const float* m1_w1   = (const float*)d_in[11];
  const float* m1_b1   = (const float*)d_in[12];
  const float* m1_w2   = (const float*)d_in[13];
  const float* m1_b2   = (const float*)d_in[14];
  const float* n2_g    = (const float*)d_in[15];
  const float* n2_b    = (const float*)d_in[16];
  const float* ca_in_w = (const float*)d_in[17];
  const float* ca_in_b = (const float*)d_in[18];
  const float* ca_out_w= (const float*)d_in[19];
  const float* ca_out_b= (const float*)d_in[20];
  const float* n3_g    = (const float*)d_in[21];
  const float* n3_b    = (const float*)d_in[22];
  const float* m2_w1   = (const float*)d_in[23];
  const float* m2_b1   = (const float*)d_in[24];
  const float* m2_w2   = (const float*)d_in[25];
  const float* m2_b2   = (const float*)d_in[26];
  const float* n4_g    = (const float*)d_in[27];
  const float* n4_b    = (const float*)d_in[28];
  const float* fin_w   = (const float*)d_in[29];
  const float* fin_b   = (const float*)d_in[30];
  float* outp = (float*)d_out;

  // workspace layout (bytes, all 16B-aligned); total 17,965,056 B (~17.1 MiB)
  //   xf     [0,        2097152)  f32 4096x128
  //   tab    [2097152,  2105344)  f32 10x128 (+pad)
  //   wsb    [2105344,  2760704)  bf16 327680 weights (640 KB)
  //   xb     [2760704,  3809280)  bf16 4096x128
  //   attnb  [3809280,  4857856)  bf16 4096x128
  //   qkvb   [4857856,  8003584)  bf16 4096x384
  //   vT     [8003584,  9052160)  bf16 128x4096
  //   opart  [9052160, 17440768)  bf16 8192x16x32 (h1b aliases, dead after fin)
  //   lpart  [17440768,17965056)  f32 8192x16
  char* w = (char*)d_ws;
  float*  xf    = (float*)(w);
  float*  tab   = (float*)(w + 2097152);
  bf16_t* wsb   = (bf16_t*)(w + 2105344);
  bf16_t* xb    = (bf16_t*)(w + 2760704);
  bf16_t* attnb = (bf16_t*)(w + 3809280);
  bf16_t* qkvb  = (bf16_t*)(w + 4857856);
  bf16_t* vT    = (bf16_t*)(w + 8003584);
  bf16_t* opart = (bf16_t*)(w + 9052160);
  bf16_t* h1b   = (bf16_t*)(w + 9052160);   // alias (opart dead after fin)
  float*  lpart = (float*)(w + 17440768);

  bf16_t* w_sain  = wsb;
  bf16_t* w_saout = wsb + 49152;
  bf16_t* w_m1w1  = wsb + 65536;
  bf16_t* w_m1w2  = wsb + 131072;
  bf16_t* w_m2w1  = wsb + 196608;
  bf16_t* w_m2w2  = wsb + 262144;

  // embed + weight cvt + ca table (independent, one kernel)
  k_init<<<2369, 256, 0, stream>>>(coords, ce_w, ce_b, xf, xb,
                                   sa_in_w, sa_out_w, m1_w1, m1_w2, m2_w1, m2_w2,
                                   wsb, emb, ca_in_w + 256 * 128, ca_in_b + 256,
                                   ca_out_w, ca_out_b, tab);
  // qkv projection (+ transposed V)
  k_gemm<128, EPI_BF16><<<dim3(64, 6), 256, 0, stream>>>(xb, w_sain, sa_in_b,
                                                         qkvb, vT, 384);
  // self-attention: ksplit=8 partials, then combine
  k_attn<<<2048, 256, 0, stream>>>(qkvb, vT, opart, lpart);
  k_attn_fin<<<2048, 256, 0, stream>>>(opart, lpart, attnb);
  // out-proj + residual + ln1
  k_gemmln<128, 0><<<64, 256, 0, stream>>>(attnb, w_saout, sa_out_b, xf,
                                           n1_g, n1_b, nullptr, nullptr,
                                           nullptr, nullptr, nullptr, nullptr,
                                           xf, xb, nullptr);
  // mlp1 up (GELU)
  k_gemm<128, EPI_GELU_BF16><<<dim3(64, 8), 256, 0, stream>>>(xb, w_m1w1, m1_b1,
                                                              h1b, nullptr, 512);
  // mlp1 down + ln2 + (ca gather) + ln3
  k_gemmln<512, 1><<<64, 256, 0, stream>>>(h1b, w_m1w2, m1_b2, xf,
                                           n2_g, n2_b, labels, tab,
                                           n3_g, n3_b, nullptr, nullptr,
                                           xf, xb, nullptr);
  // mlp2 up (GELU)
  k_gemm<128, EPI_GELU_BF16><<<dim3(64, 8), 256, 0, stream>>>(xb, w_m2w1, m2_b1,
                                                              h1b, nullptr, 512);
  // mlp2 down + ln4 + fin + sigmoid
  k_gemmln<512, 2><<<64, 256, 0, stream>>>(h1b, w_m2w2, m2_b2, xf,
                                           n4_g, n4_b, nullptr, nullptr,
                                           nullptr, nullptr, fin_w, fin_b,
                                           nullptr, nullptr, outp);

  (void)in_sizes; (void)n_in; (void)out_size; (void)ws_size;
}

// Round 6
// 236.183 us; speedup vs baseline: 1.1292x; 1.1292x over previous
//
#include <hip/hip_runtime.h>
#include <hip/hip_bf16.h>

// INRformer forward, MI355X gfx950. Inputs f32, labels i32, output f32 (4096x1).
// B=4096, D=128, H=4, HD=32, NC=10. Internal activations bf16 for MFMA.
// Round 6: k_attn rewrite — block waves share (h,ks) K/V lines (L1 reuse),
// Q=32/wave, S^T mfma order -> ds_write_b64 P-park, per-lane l accumulation.
// Non-attn pipeline unchanged (measured ~free; ~199us fixed replay overhead).

typedef __bf16 bf16_t;
typedef __bf16 bf16x8 __attribute__((ext_vector_type(8)));
typedef __bf16 bf16x4 __attribute__((ext_vector_type(4)));
typedef __bf16 bf16x2 __attribute__((ext_vector_type(2)));
typedef float  f32x4  __attribute__((ext_vector_type(4)));
typedef float  f32x2  __attribute__((ext_vector_type(2)));

__device__ __forceinline__ f32x4 mfma16(bf16x8 a, bf16x8 b, f32x4 c) {
  return __builtin_amdgcn_mfma_f32_16x16x32_bf16(a, b, c, 0, 0, 0);
}

// --------------------------------------- init: embed+PE | weight cvt | catab
__global__ __launch_bounds__(256) void k_init(const float* __restrict__ coords,
                                              const float* __restrict__ ce_w,
                                              const float* __restrict__ ce_b,
                                              float* __restrict__ xf,
                                              bf16_t* __restrict__ xb,
                                              const float* __restrict__ s0,
                                              const float* __restrict__ s1,
                                              const float* __restrict__ s2,
                                              const float* __restrict__ s3,
                                              const float* __restrict__ s4,
                                              const float* __restrict__ s5,
                                              bf16_t* __restrict__ wdst,
                                              const float* __restrict__ emb,
                                              const float* __restrict__ wvp,
                                              const float* __restrict__ bvp,
                                              const float* __restrict__ cow,
                                              const float* __restrict__ cob,
                                              float* __restrict__ tab) {
  const int bid = blockIdx.x;
  const int tid = threadIdx.x;
  if (bid < 2048) {  // ---- embed + positional encoding
    int row = bid * 2 + (tid >> 7);
    int d   = tid & 127;
    float c0 = coords[row * 2 + 0];
    float c1 = coords[row * 2 + 1];
    int   j  = d >> 1;
    float inv = exp2f(-0.20762050593045953f * (float)j);  // 10000^(-2j/128)
    float pe  = (d & 1) ? cosf(c1 * inv) : sinf(c0 * inv);
    float x = c0 * ce_w[2 * d] + c1 * ce_w[2 * d + 1] + ce_b[d] + pe;
    xf[(size_t)row * 128 + d] = x;
    xb[(size_t)row * 128 + d] = (bf16_t)x;
  } else if (bid < 2368) {  // ---- weight f32->bf16 (4 elems/thread)
    int i = (bid - 2048) * 256 + tid;  // < 81920
    const float* src; int off;
    if      (i < 12288) { src = s0; off = i; }
    else if (i < 16384) { src = s1; off = i - 12288; }
    else if (i < 32768) { src = s2; off = i - 16384; }
    else if (i < 49152) { src = s3; off = i - 32768; }
    else if (i < 65536) { src = s4; off = i - 49152; }
    else                { src = s5; off = i - 65536; }
    f32x4 v = *(const f32x4*)(src + (size_t)off * 4);
    bf16x4 o = {(bf16_t)v[0], (bf16_t)v[1], (bf16_t)v[2], (bf16_t)v[3]};
    *(bf16x4*)(wdst + (size_t)i * 4) = o;
  } else {  // ---- ca table: tab[c] = (emb[c]@wv^T+bv)@ca_out^T+ca_out_b
    __shared__ float embs[10][128];
    __shared__ float t1[10][128];
    for (int i = tid; i < 1280; i += 256) embs[i >> 7][i & 127] = emb[i];
    __syncthreads();
    for (int o = tid; o < 1280; o += 256) {
      int c = o >> 7, n = o & 127;
      float acc = bvp[n];
      const float* wr = wvp + n * 128;
      for (int k2 = 0; k2 < 128; k2++) acc += embs[c][k2] * wr[k2];
      t1[c][n] = acc;
    }
    __syncthreads();
    for (int o = tid; o < 1280; o += 256) {
      int c = o >> 7, dd = o & 127;
      float acc = cob[dd];
      const float* wr = cow + dd * 128;
      for (int n = 0; n < 128; n++) acc += t1[c][n] * wr[n];
      tab[o] = acc;
    }
  }
}

// ------------------------------------------------------- generic MFMA GEMM
enum { EPI_BF16 = 1, EPI_GELU_BF16 = 2 };

template <int K, int EPI>
__global__ __launch_bounds__(256) void k_gemm(const bf16_t* __restrict__ X,
                                              const bf16_t* __restrict__ Wb,
                                              const float* __restrict__ bias,
                                              bf16_t* __restrict__ outB,
                                              bf16_t* __restrict__ vTout,
                                              int N) {
  const int tid  = threadIdx.x;
  const int lane = tid & 63;
  const int wv   = tid >> 6;
  const int l15  = lane & 15;
  const int quad = lane >> 4;
  const int xbase = blockIdx.x * 64 + (wv >> 1) * 32;  // output rows
  const int wbase = blockIdx.y * 64 + (wv & 1) * 32;   // output cols

  const bf16_t* wr0 = Wb + (size_t)(wbase + l15) * K + quad * 8;
  const bf16_t* xr0 = X  + (size_t)(xbase + l15) * K + quad * 8;

  f32x4 acc[2][2];  // [i: col tile][t: row tile]
  const f32x4 zero4 = {0.f, 0.f, 0.f, 0.f};
  for (int i = 0; i < 2; i++)
    for (int t = 0; t < 2; t++) acc[i][t] = zero4;

#pragma unroll 4
  for (int kk = 0; kk < K; kk += 32) {
    bf16x8 a0 = *(const bf16x8*)(wr0 + kk);
    bf16x8 a1 = *(const bf16x8*)(wr0 + 16 * K + kk);
    bf16x8 b0 = *(const bf16x8*)(xr0 + kk);
    bf16x8 b1 = *(const bf16x8*)(xr0 + 16 * K + kk);
    acc[0][0] = mfma16(a0, b0, acc[0][0]);
    acc[0][1] = mfma16(a0, b1, acc[0][1]);
    acc[1][0] = mfma16(a1, b0, acc[1][0]);
    acc[1][1] = mfma16(a1, b1, acc[1][1]);
  }

  f32x4 bv[2];
  bv[0] = *(const f32x4*)(bias + wbase + quad * 4);
  bv[1] = *(const f32x4*)(bias + wbase + 16 + quad * 4);
#pragma unroll
  for (int t = 0; t < 2; t++) {
    int row = xbase + t * 16 + l15;
#pragma unroll
    for (int i = 0; i < 2; i++) {
      int col0 = wbase + i * 16 + quad * 4;
      f32x4 v = acc[i][t] + bv[i];
      if (EPI == EPI_GELU_BF16) {
#pragma unroll
        for (int r = 0; r < 4; r++)
          v[r] = 0.5f * v[r] * (1.0f + erff(v[r] * 0.70710678118654752f));
      }
      bf16x4 o = {(bf16_t)v[0], (bf16_t)v[1], (bf16_t)v[2], (bf16_t)v[3]};
      *(bf16x4*)(outB + (size_t)row * N + col0) = o;
      if (vTout && col0 >= 256) {  // V block: also store transposed
#pragma unroll
        for (int r = 0; r < 4; r++)
          vTout[(size_t)(col0 - 256 + r) * 4096 + row] = (bf16_t)v[r];
      }
    }
  }
}

// --------------------------------------- GEMM (N=128) + residual + LN fused
template <int K, int MODE>
__global__ __launch_bounds__(256) void k_gemmln(const bf16_t* __restrict__ X,
                                                const bf16_t* __restrict__ Wb,
                                                const float* __restrict__ bias,
                                                const float* __restrict__ resid,
                                                const float* __restrict__ g1,
                                                const float* __restrict__ b1,
                                                const int* __restrict__ labels,
                                                const float* __restrict__ tab,
                                                const float* __restrict__ g2,
                                                const float* __restrict__ b2,
                                                const float* __restrict__ fw,
                                                const float* __restrict__ fb,
                                                float* __restrict__ xf_out,
                                                bf16_t* __restrict__ xb_out,
                                                float* __restrict__ out) {
  __shared__ float red[2][64][2];  // [metric][row-in-block][col-half]

  const int tid  = threadIdx.x;
  const int lane = tid & 63;
  const int wv   = tid >> 6;
  const int l15  = lane & 15;
  const int quad = lane >> 4;
  const int rhalf = wv >> 1, chalf = wv & 1;
  const int rb = blockIdx.x * 64 + rhalf * 32;
  const int cb = chalf * 64;

  const bf16_t* xr0 = X  + (size_t)(rb + l15) * K + quad * 8;
  const bf16_t* wr0 = Wb + (size_t)(cb + l15) * K + quad * 8;

  f32x4 acc[2][4];  // [t: row tile][i: col tile]
  const f32x4 zero4 = {0.f, 0.f, 0.f, 0.f};
  for (int t = 0; t < 2; t++)
    for (int i = 0; i < 4; i++) acc[t][i] = zero4;

#pragma unroll 4
  for (int kk = 0; kk < K; kk += 32) {
    bf16x8 b0 = *(const bf16x8*)(xr0 + kk);
    bf16x8 b1 = *(const bf16x8*)(xr0 + 16 * K + kk);
#pragma unroll
    for (int i = 0; i < 4; i++) {
      bf16x8 a = *(const bf16x8*)(wr0 + (size_t)i * 16 * K + kk);
      acc[0][i] = mfma16(a, b0, acc[0][i]);
      acc[1][i] = mfma16(a, b1, acc[1][i]);
    }
  }

  // bias + residual; per-row sums
  f32x4 v[2][4];
  float s[2] = {0.f, 0.f}, sq[2] = {0.f, 0.f};
#pragma unroll
  for (int t = 0; t < 2; t++) {
    int row = rb + t * 16 + l15;
#pragma unroll
    for (int i = 0; i < 4; i++) {
      int c = cb + i * 16 + quad * 4;
      f32x4 vv = acc[t][i] + *(const f32x4*)(bias + c)
               + *(const f32x4*)(resid + (size_t)row * 128 + c);
      v[t][i] = vv;
      s[t]  += (vv[0] + vv[1]) + (vv[2] + vv[3]);
      sq[t] += (vv[0] * vv[0] + vv[1] * vv[1]) + (vv[2] * vv[2] + vv[3] * vv[3]);
    }
  }
#pragma unroll
  for (int t = 0; t < 2; t++) {
    s[t]  += __shfl_xor(s[t], 16, 64);  s[t]  += __shfl_xor(s[t], 32, 64);
    sq[t] += __shfl_xor(sq[t], 16, 64); sq[t] += __shfl_xor(sq[t], 32, 64);
    if (quad == 0) {
      red[0][rhalf * 32 + t * 16 + l15][chalf] = s[t];
      red[1][rhalf * 32 + t * 16 + l15][chalf] = sq[t];
    }
  }
  __syncthreads();
  float mean[2], rstd[2];
#pragma unroll
  for (int t = 0; t < 2; t++) {
    int rl = rhalf * 32 + t * 16 + l15;
    float S  = red[0][rl][0] + red[0][rl][1];
    float SQ = red[1][rl][0] + red[1][rl][1];
    mean[t] = S * (1.0f / 128.0f);
    rstd[t] = rsqrtf(SQ * (1.0f / 128.0f) - mean[t] * mean[t] + 1e-5f);
  }

  f32x4 g4[4], b4[4];
#pragma unroll
  for (int i = 0; i < 4; i++) {
    int c = cb + i * 16 + quad * 4;
    g4[i] = *(const f32x4*)(g1 + c);
    b4[i] = *(const f32x4*)(b1 + c);
  }

  if (MODE == 0) {
#pragma unroll
    for (int t = 0; t < 2; t++) {
      int row = rb + t * 16 + l15;
#pragma unroll
      for (int i = 0; i < 4; i++) {
        int c = cb + i * 16 + quad * 4;
        f32x4 y = (v[t][i] - mean[t]) * rstd[t] * g4[i] + b4[i];
        *(f32x4*)(xf_out + (size_t)row * 128 + c) = y;
        bf16x4 o = {(bf16_t)y[0], (bf16_t)y[1], (bf16_t)y[2], (bf16_t)y[3]};
        *(bf16x4*)(xb_out + (size_t)row * 128 + c) = o;
      }
    }
  } else if (MODE == 1) {
    // second LN with gathered class-table branch
    int lab[2];
    float s2v[2] = {0.f, 0.f}, sq2[2] = {0.f, 0.f};
#pragma unroll
    for (int t = 0; t < 2; t++) {
      lab[t] = labels[rb + t * 16 + l15];
#pragma unroll
      for (int i = 0; i < 4; i++) {
        int c = cb + i * 16 + quad * 4;
        f32x4 y = (v[t][i] - mean[t]) * rstd[t] * g4[i] + b4[i];
        y = y + *(const f32x4*)(tab + (size_t)lab[t] * 128 + c);
        v[t][i] = y;
        s2v[t] += (y[0] + y[1]) + (y[2] + y[3]);
        sq2[t] += (y[0] * y[0] + y[1] * y[1]) + (y[2] * y[2] + y[3] * y[3]);
      }
    }
    __syncthreads();  // all first-round red reads done
#pragma unroll
    for (int t = 0; t < 2; t++) {
      s2v[t] += __shfl_xor(s2v[t], 16, 64); s2v[t] += __shfl_xor(s2v[t], 32, 64);
      sq2[t] += __shfl_xor(sq2[t], 16, 64); sq2[t] += __shfl_xor(sq2[t], 32, 64);
      if (quad == 0) {
        red[0][rhalf * 32 + t * 16 + l15][chalf] = s2v[t];
        red[1][rhalf * 32 + t * 16 + l15][chalf] = sq2[t];
      }
    }
    __syncthreads();
#pragma unroll
    for (int t = 0; t < 2; t++) {
      int rl = rhalf * 32 + t * 16 + l15;
      float S  = red[0][rl][0] + red[0][rl][1];
      float SQ = red[1][rl][0] + red[1][rl][1];
      mean[t] = S * (1.0f / 128.0f);
      rstd[t] = rsqrtf(SQ * (1.0f / 128.0f) - mean[t] * mean[t] + 1e-5f);
    }
#pragma unroll
    for (int t = 0; t < 2; t++) {
      int row = rb + t * 16 + l15;
#pragma unroll
      for (int i = 0; i < 4; i++) {
        int c = cb + i * 16 + quad * 4;
        f32x4 y = (v[t][i] - mean[t]) * rstd[t] * (*(const f32x4*)(g2 + c))
                + *(const f32x4*)(b2 + c);
        *(f32x4*)(xf_out + (size_t)row * 128 + c) = y;
        bf16x4 o = {(bf16_t)y[0], (bf16_t)y[1], (bf16_t)y[2], (bf16_t)y[3]};
        *(bf16x4*)(xb_out + (size_t)row * 128 + c) = o;
      }
    }
  } else {  // MODE 2: LN -> fin dot -> sigmoid
    float dot[2] = {0.f, 0.f};
#pragma unroll
    for (int t = 0; t < 2; t++) {
#pragma unroll
      for (int i = 0; i < 4; i++) {
        int c = cb + i * 16 + quad * 4;
        f32x4 y = (v[t][i] - mean[t]) * rstd[t] * g4[i] + b4[i];
        f32x4 fw4 = *(const f32x4*)(fw + c);
        dot[t] += (y[0] * fw4[0] + y[1] * fw4[1]) + (y[2] * fw4[2] + y[3] * fw4[3]);
      }
    }
    __syncthreads();
#pragma unroll
    for (int t = 0; t < 2; t++) {
      dot[t] += __shfl_xor(dot[t], 16, 64); dot[t] += __shfl_xor(dot[t], 32, 64);
      if (quad == 0) red[0][rhalf * 32 + t * 16 + l15][chalf] = dot[t];
    }
    __syncthreads();
    if (chalf == 0 && quad == 0) {
      float fbv = fb[0];
#pragma unroll
      for (int t = 0; t < 2; t++) {
        int rl = rhalf * 32 + t * 16 + l15;
        float logit = red[0][rl][0] + red[0][rl][1] + fbv;
        out[blockIdx.x * 64 + rl] = 1.0f / (1.0f + expf(-logit));
      }
    }
  }
}

// ----------------------------------------- flash-decoding attention partial
// One wave = (head h, 32-query tile qt, 512-key split ks); 4096 wave-tasks.
// Block's 4 waves share (h,ks) with consecutive qt -> identical K/V cache
// lines (L1 temporal reuse x4). m=0 softmax (scores tiny; |s|<~1).
// S^T order: mfma16(kf,qf) -> lane holds 4 consecutive keys for query l15
// -> P parked with one ds_write_b64 per 16x16 tile; l accumulates per-lane.
// PV: mfma16(p_frag, vT_frag) -> O[q=quad*4+r][d=l15].
__global__ __launch_bounds__(256, 4) void k_attn(const bf16_t* __restrict__ qkv,
                                                 const bf16_t* __restrict__ vT,
                                                 bf16_t* __restrict__ opart,
                                                 float* __restrict__ lpart) {
  __shared__ bf16_t pt[4][2][16][72];  // [wave][qtile][query][key] pad 72

  const int tid  = threadIdx.x;
  const int lane = tid & 63;
  const int wv   = tid >> 6;
  const int l15  = lane & 15;
  const int quad = lane >> 4;
  const int blk  = blockIdx.x;         // 0..1023
  const int h    = blk & 3;
  const int ks   = (blk >> 2) & 7;
  const int qt   = (blk >> 5) * 4 + wv;  // 0..127 (32-query tiles)
  const int q0   = qt * 32;
  const int kb   = ks * 512;
  const int task = (qt * 8 + ks) * 4 + h;

  // Q frags (B-operand layout: query at l15, d at quad*8+j), prescaled
  bf16x8 qfA, qfB;
  {
    bf16x8 ra = *(const bf16x8*)(qkv + (size_t)(q0 + l15) * 384 + h * 32 + quad * 8);
    bf16x8 rb = *(const bf16x8*)(qkv + (size_t)(q0 + 16 + l15) * 384 + h * 32 + quad * 8);
#pragma unroll
    for (int j = 0; j < 8; j++) {
      qfA[j] = (bf16_t)((float)ra[j] * 0.17677669529663687f);
      qfB[j] = (bf16_t)((float)rb[j] * 0.17677669529663687f);
    }
  }

  const f32x4 zero4 = {0.f, 0.f, 0.f, 0.f};
  f32x4 oA0 = zero4, oA1 = zero4, oB0 = zero4, oB1 = zero4;
  float laccA = 0.f, laccB = 0.f;

  const bf16_t* kbase = qkv + 128 + h * 32 + quad * 8 + (size_t)l15 * 384;
  const bf16_t* vbase = vT + (size_t)(h * 32 + l15) * 4096 + quad * 8;

  for (int kk = 0; kk < 512; kk += 64) {
    // ---- issue all loads first (independent of softmax chain)
    const bf16_t* kp = kbase + (size_t)(kb + kk) * 384;
    bf16x8 kf0 = *(const bf16x8*)(kp);
    bf16x8 kf1 = *(const bf16x8*)(kp + 16 * 384);
    bf16x8 kf2 = *(const bf16x8*)(kp + 32 * 384);
    bf16x8 kf3 = *(const bf16x8*)(kp + 48 * 384);
    const bf16_t* vp = vbase + kb + kk;
    bf16x8 v00 = *(const bf16x8*)(vp);               // k 0-31,  d l15
    bf16x8 v01 = *(const bf16x8*)(vp + 16 * 4096);   // k 0-31,  d 16+l15
    bf16x8 v10 = *(const bf16x8*)(vp + 32);          // k 32-63, d l15
    bf16x8 v11 = *(const bf16x8*)(vp + 16 * 4096 + 32);

    // ---- S^T: reg r = K[kt*16+quad*4+r] . Q[l15]
    f32x4 sA[4], sB[4];
    sA[0] = mfma16(kf0, qfA, zero4);
    sA[1] = mfma16(kf1, qfA, zero4);
    sA[2] = mfma16(kf2, qfA, zero4);
    sA[3] = mfma16(kf3, qfA, zero4);
    sB[0] = mfma16(kf0, qfB, zero4);
    sB[1] = mfma16(kf1, qfB, zero4);
    sB[2] = mfma16(kf2, qfB, zero4);
    sB[3] = mfma16(kf3, qfB, zero4);

    // ---- p = exp(s); park P^T slabs as b64; accumulate per-lane l
#pragma unroll
    for (int t = 0; t < 4; t++) {
      float a0 = __expf(sA[t][0]), a1 = __expf(sA[t][1]);
      float a2 = __expf(sA[t][2]), a3 = __expf(sA[t][3]);
      laccA += (a0 + a1) + (a2 + a3);
      bf16x4 pa = {(bf16_t)a0, (bf16_t)a1, (bf16_t)a2, (bf16_t)a3};
      *(bf16x4*)&pt[wv][0][l15][t * 16 + quad * 4] = pa;
      float b0 = __expf(sB[t][0]), b1 = __expf(sB[t][1]);
      float b2 = __expf(sB[t][2]), b3 = __expf(sB[t][3]);
      laccB += (b0 + b1) + (b2 + b3);
      bf16x4 pb = {(bf16_t)b0, (bf16_t)b1, (bf16_t)b2, (bf16_t)b3};
      *(bf16x4*)&pt[wv][1][l15][t * 16 + quad * 4] = pb;
    }

    // ---- read back in A-operand layout (query l15, keys quad*8+j)
    bf16x8 pA0 = *(const bf16x8*)&pt[wv][0][l15][quad * 8];
    bf16x8 pA1 = *(const bf16x8*)&pt[wv][0][l15][32 + quad * 8];
    bf16x8 pB0 = *(const bf16x8*)&pt[wv][1][l15][quad * 8];
    bf16x8 pB1 = *(const bf16x8*)&pt[wv][1][l15][32 + quad * 8];

    oA0 = mfma16(pA0, v00, oA0);
    oA0 = mfma16(pA1, v10, oA0);
    oA1 = mfma16(pA0, v01, oA1);
    oA1 = mfma16(pA1, v11, oA1);
    oB0 = mfma16(pB0, v00, oB0);
    oB0 = mfma16(pB1, v10, oB0);
    oB1 = mfma16(pB0, v01, oB1);
    oB1 = mfma16(pB1, v11, oB1);
  }

  // l: sum the 4 quad-partials for each query lane
  laccA += __shfl_xor(laccA, 16, 64); laccA += __shfl_xor(laccA, 32, 64);
  laccB += __shfl_xor(laccB, 16, 64); laccB += __shfl_xor(laccB, 32, 64);
  if (quad == 0) {
    lpart[task * 32 + l15]      = laccA;
    lpart[task * 32 + 16 + l15] = laccB;
  }

  size_t ob = (size_t)task * 1024;  // [32 queries][32 dims]
#pragma unroll
  for (int r = 0; r < 4; r++) {
    int qa = quad * 4 + r;
    opart[ob + qa * 32 + l15]             = (bf16_t)oA0[r];
    opart[ob + qa * 32 + 16 + l15]        = (bf16_t)oA1[r];
    opart[ob + (16 + qa) * 32 + l15]      = (bf16_t)oB0[r];
    opart[ob + (16 + qa) * 32 + 16 + l15] = (bf16_t)oB1[r];
  }
}

// ------------------------------------------------ combine ksplit partials
__global__ __launch_bounds__(256) void k_attn_fin(const bf16_t* __restrict__ opart,
                                                  const float* __restrict__ lpart,
                                                  bf16_t* __restrict__ attnb) {
  int idx = blockIdx.x * 256 + threadIdx.x;  // ((h*4096+q)*32+d), < 524288
  int d  = idx & 31;
  int q  = (idx >> 5) & 4095;
  int h  = idx >> 17;
  int qt = q >> 5, ql = q & 31;
  float O = 0.f, L = 0.f;
#pragma unroll
  for (int ks = 0; ks < 8; ks++) {
    int t = (qt * 8 + ks) * 4 + h;
    O += (float)opart[(size_t)t * 1024 + ql * 32 + d];
    L += lpart[t * 32 + ql];
  }
  attnb[(size_t)q * 128 + h * 32 + d] = (bf16_t)(O / L);
}

// --------------------------------------------------------------------------
extern "C" void kernel_launch(void* const* d_in, const int* in_sizes, int n_in,
                              void* d_out, int out_size, void* d_ws, size_t ws_size,
                              hipStream_t stream) {
  const float* coords  = (const float*)d_in[0];
  const int*   labels  = (const int*)d_in[1];
  const float* ce_w    = (const float*)d_in[2];
  const float* ce_b    = (const float*)d_in[3];
  const float* emb     = (const float*)d_in[4];
  const float* sa_in_w = (const float*)d_in[5];
  const float* sa_in_b = (const float*)d_in[6];
  const float* sa_out_w= (const float*)d_in[7];
  const float* sa_out_b= (const float*)d_in[8];
  const float* n1_g    = (const float*)d_in[9];
  const float* n1_b    = (const float*)d_in[10];
  const float* m1_w1   = (const float*)d_in[11];
  const float* m1_b1   = (const float*)d_in[12];
  const float* m1_w2   = (const float*)d_in[13];
  const float* m1_b2   = (const float*)d_in[14];
  const float* n2_g    = (const float*)d_in[15];
  const float* n2_b    = (const float*)d_in[16];
  const float* ca_in_w = (const float*)d_in[17];
  const float* ca_in_b = (const float*)d_in[18];
  const float* ca_out_w= (const float*)d_in[19];
  const float* ca_out_b= (const float*)d_in[20];
  const float* n3_g    = (const float*)d_in[21];
  const float* n3_b    = (const float*)d_in[22];
  const float* m2_w1   = (const float*)d_in[23];
  const float* m2_b1   = (const float*)d_in[24];
  const float* m2_w2   = (const float*)d_in[25];
  const float* m2_b2   = (const float*)d_in[26];
  const float* n4_g    = (const float*)d_in[27];
  const float* n4_b    = (const float*)d_in[28];
  const float* fin_w   = (const float*)d_in[29];
  const float* fin_b   = (const float*)d_in[30];
  float* outp = (float*)d_out;

  // workspace layout (bytes, 16B-aligned); total 17,965,056 B
  char* w = (char*)d_ws;
  float*  xf    = (float*)(w);
  float*  tab   = (float*)(w + 2097152);
  bf16_t* wsb   = (bf16_t*)(w + 2105344);
  bf16_t* xb    = (bf16_t*)(w + 2760704);
  bf16_t* attnb = (bf16_t*)(w + 3809280);
  bf16_t* qkvb  = (bf16_t*)(w + 4857856);
  bf16_t* vT    = (bf16_t*)(w + 8003584);
  bf16_t* opart = (bf16_t*)(w + 9052160);   // 8 MB: 4096 tasks x 32q x 32d
  bf16_t* h1b   = (bf16_t*)(w + 9052160);   // alias (opart dead after fin)
  float*  lpart = (float*)(w + 17440768);   // 512 KB: 4096 x 32

  bf16_t* w_sain  = wsb;
  bf16_t* w_saout = wsb + 49152;
  bf16_t* w_m1w1  = wsb + 65536;
  bf16_t* w_m1w2  = wsb + 131072;
  bf16_t* w_m2w1  = wsb + 196608;
  bf16_t* w_m2w2  = wsb + 262144;

  // embed + weight cvt + ca table (independent, one kernel)
  k_init<<<2369, 256, 0, stream>>>(coords, ce_w, ce_b, xf, xb,
                                   sa_in_w, sa_out_w, m1_w1, m1_w2, m2_w1, m2_w2,
                                   wsb, emb, ca_in_w + 256 * 128, ca_in_b + 256,
                                   ca_out_w, ca_out_b, tab);
  // qkv projection (+ transposed V)
  k_gemm<128, EPI_BF16><<<dim3(64, 6), 256, 0, stream>>>(xb, w_sain, sa_in_b,
                                                         qkvb, vT, 384);
  // self-attention: ksplit=8 partials, then combine
  k_attn<<<1024, 256, 0, stream>>>(qkvb, vT, opart, lpart);
  k_attn_fin<<<2048, 256, 0, stream>>>(opart, lpart, attnb);
  // out-proj + residual + ln1
  k_gemmln<128, 0><<<64, 256, 0, stream>>>(attnb, w_saout, sa_out_b, xf,
                                           n1_g, n1_b, nullptr, nullptr,
                                           nullptr, nullptr, nullptr, nullptr,
                                           xf, xb, nullptr);
  // mlp1 up (GELU)
  k_gemm<128, EPI_GELU_BF16><<<dim3(64, 8), 256, 0, stream>>>(xb, w_m1w1, m1_b1,
                                                              h1b, nullptr, 512);
  // mlp1 down + ln2 + (ca gather) + ln3
  k_gemmln<512, 1><<<64, 256, 0, stream>>>(h1b, w_m1w2, m1_b2, xf,
                                           n2_g, n2_b, labels, tab,
                                           n3_g, n3_b, nullptr, nullptr,
                                           xf, xb, nullptr);
  // mlp2 up (GELU)
  k_gemm<128, EPI_GELU_BF16><<<dim3(64, 8), 256, 0, stream>>>(xb, w_m2w1, m2_b1,
                                                              h1b, nullptr, 512);
  // mlp2 down + ln4 + fin + sigmoid
  k_gemmln<512, 2><<<64, 256, 0, stream>>>(h1b, w_m2w2, m2_b2, xf,
                                           n4_g, n4_b, nullptr, nullptr,
                                           nullptr, nullptr, fin_w, fin_b,
                                           nullptr, nullptr, outp);

  (void)in_sizes; (void)n_in; (void)out_size; (void)ws_size;
}

// Round 7
// 224.635 us; speedup vs baseline: 1.1872x; 1.0514x over previous
//
#include <hip/hip_runtime.h>
#include <hip/hip_bf16.h>

// INRformer forward, MI355X gfx950. Inputs f32, labels i32, output f32 (4096x1).
// B=4096, D=128, H=4, HD=32, NC=10. Internal activations bf16 for MFMA.
// Round 7: k_attn with block-cooperative LDS staging of K/V^T (coalesced,
// one copy per block instead of per wave; fragments via ds_read_b128).
// Non-attn pipeline byte-identical to passing round 5/6.

typedef __bf16 bf16_t;
typedef __bf16 bf16x8 __attribute__((ext_vector_type(8)));
typedef __bf16 bf16x4 __attribute__((ext_vector_type(4)));
typedef __bf16 bf16x2 __attribute__((ext_vector_type(2)));
typedef float  f32x4  __attribute__((ext_vector_type(4)));
typedef float  f32x2  __attribute__((ext_vector_type(2)));

__device__ __forceinline__ f32x4 mfma16(bf16x8 a, bf16x8 b, f32x4 c) {
  return __builtin_amdgcn_mfma_f32_16x16x32_bf16(a, b, c, 0, 0, 0);
}

// --------------------------------------- init: embed+PE | weight cvt | catab
__global__ __launch_bounds__(256) void k_init(const float* __restrict__ coords,
                                              const float* __restrict__ ce_w,
                                              const float* __restrict__ ce_b,
                                              float* __restrict__ xf,
                                              bf16_t* __restrict__ xb,
                                              const float* __restrict__ s0,
                                              const float* __restrict__ s1,
                                              const float* __restrict__ s2,
                                              const float* __restrict__ s3,
                                              const float* __restrict__ s4,
                                              const float* __restrict__ s5,
                                              bf16_t* __restrict__ wdst,
                                              const float* __restrict__ emb,
                                              const float* __restrict__ wvp,
                                              const float* __restrict__ bvp,
                                              const float* __restrict__ cow,
                                              const float* __restrict__ cob,
                                              float* __restrict__ tab) {
  const int bid = blockIdx.x;
  const int tid = threadIdx.x;
  if (bid < 2048) {  // ---- embed + positional encoding
    int row = bid * 2 + (tid >> 7);
    int d   = tid & 127;
    float c0 = coords[row * 2 + 0];
    float c1 = coords[row * 2 + 1];
    int   j  = d >> 1;
    float inv = exp2f(-0.20762050593045953f * (float)j);  // 10000^(-2j/128)
    float pe  = (d & 1) ? cosf(c1 * inv) : sinf(c0 * inv);
    float x = c0 * ce_w[2 * d] + c1 * ce_w[2 * d + 1] + ce_b[d] + pe;
    xf[(size_t)row * 128 + d] = x;
    xb[(size_t)row * 128 + d] = (bf16_t)x;
  } else if (bid < 2368) {  // ---- weight f32->bf16 (4 elems/thread)
    int i = (bid - 2048) * 256 + tid;  // < 81920
    const float* src; int off;
    if      (i < 12288) { src = s0; off = i; }
    else if (i < 16384) { src = s1; off = i - 12288; }
    else if (i < 32768) { src = s2; off = i - 16384; }
    else if (i < 49152) { src = s3; off = i - 32768; }
    else if (i < 65536) { src = s4; off = i - 49152; }
    else                { src = s5; off = i - 65536; }
    f32x4 v = *(const f32x4*)(src + (size_t)off * 4);
    bf16x4 o = {(bf16_t)v[0], (bf16_t)v[1], (bf16_t)v[2], (bf16_t)v[3]};
    *(bf16x4*)(wdst + (size_t)i * 4) = o;
  } else {  // ---- ca table: tab[c] = (emb[c]@wv^T+bv)@ca_out^T+ca_out_b
    __shared__ float embs[10][128];
    __shared__ float t1[10][128];
    for (int i = tid; i < 1280; i += 256) embs[i >> 7][i & 127] = emb[i];
    __syncthreads();
    for (int o = tid; o < 1280; o += 256) {
      int c = o >> 7, n = o & 127;
      float acc = bvp[n];
      const float* wr = wvp + n * 128;
      for (int k2 = 0; k2 < 128; k2++) acc += embs[c][k2] * wr[k2];
      t1[c][n] = acc;
    }
    __syncthreads();
    for (int o = tid; o < 1280; o += 256) {
      int c = o >> 7, dd = o & 127;
      float acc = cob[dd];
      const float* wr = cow + dd * 128;
      for (int n = 0; n < 128; n++) acc += t1[c][n] * wr[n];
      tab[o] = acc;
    }
  }
}

// ------------------------------------------------------- generic MFMA GEMM
enum { EPI_BF16 = 1, EPI_GELU_BF16 = 2 };

template <int K, int EPI>
__global__ __launch_bounds__(256) void k_gemm(const bf16_t* __restrict__ X,
                                              const bf16_t* __restrict__ Wb,
                                              const float* __restrict__ bias,
                                              bf16_t* __restrict__ outB,
                                              bf16_t* __restrict__ vTout,
                                              int N) {
  const int tid  = threadIdx.x;
  const int lane = tid & 63;
  const int wv   = tid >> 6;
  const int l15  = lane & 15;
  const int quad = lane >> 4;
  const int xbase = blockIdx.x * 64 + (wv >> 1) * 32;  // output rows
  const int wbase = blockIdx.y * 64 + (wv & 1) * 32;   // output cols

  const bf16_t* wr0 = Wb + (size_t)(wbase + l15) * K + quad * 8;
  const bf16_t* xr0 = X  + (size_t)(xbase + l15) * K + quad * 8;

  f32x4 acc[2][2];  // [i: col tile][t: row tile]
  const f32x4 zero4 = {0.f, 0.f, 0.f, 0.f};
  for (int i = 0; i < 2; i++)
    for (int t = 0; t < 2; t++) acc[i][t] = zero4;

#pragma unroll 4
  for (int kk = 0; kk < K; kk += 32) {
    bf16x8 a0 = *(const bf16x8*)(wr0 + kk);
    bf16x8 a1 = *(const bf16x8*)(wr0 + 16 * K + kk);
    bf16x8 b0 = *(const bf16x8*)(xr0 + kk);
    bf16x8 b1 = *(const bf16x8*)(xr0 + 16 * K + kk);
    acc[0][0] = mfma16(a0, b0, acc[0][0]);
    acc[0][1] = mfma16(a0, b1, acc[0][1]);
    acc[1][0] = mfma16(a1, b0, acc[1][0]);
    acc[1][1] = mfma16(a1, b1, acc[1][1]);
  }

  f32x4 bv[2];
  bv[0] = *(const f32x4*)(bias + wbase + quad * 4);
  bv[1] = *(const f32x4*)(bias + wbase + 16 + quad * 4);
#pragma unroll
  for (int t = 0; t < 2; t++) {
    int row = xbase + t * 16 + l15;
#pragma unroll
    for (int i = 0; i < 2; i++) {
      int col0 = wbase + i * 16 + quad * 4;
      f32x4 v = acc[i][t] + bv[i];
      if (EPI == EPI_GELU_BF16) {
#pragma unroll
        for (int r = 0; r < 4; r++)
          v[r] = 0.5f * v[r] * (1.0f + erff(v[r] * 0.70710678118654752f));
      }
      bf16x4 o = {(bf16_t)v[0], (bf16_t)v[1], (bf16_t)v[2], (bf16_t)v[3]};
      *(bf16x4*)(outB + (size_t)row * N + col0) = o;
      if (vTout && col0 >= 256) {  // V block: also store transposed
#pragma unroll
        for (int r = 0; r < 4; r++)
          vTout[(size_t)(col0 - 256 + r) * 4096 + row] = (bf16_t)v[r];
      }
    }
  }
}

// --------------------------------------- GEMM (N=128) + residual + LN fused
template <int K, int MODE>
__global__ __launch_bounds__(256) void k_gemmln(const bf16_t* __restrict__ X,
                                                const bf16_t* __restrict__ Wb,
                                                const float* __restrict__ bias,
                                                const float* __restrict__ resid,
                                                const float* __restrict__ g1,
                                                const float* __restrict__ b1,
                                                const int* __restrict__ labels,
                                                const float* __restrict__ tab,
                                                const float* __restrict__ g2,
                                                const float* __restrict__ b2,
                                                const float* __restrict__ fw,
                                                const float* __restrict__ fb,
                                                float* __restrict__ xf_out,
                                                bf16_t* __restrict__ xb_out,
                                                float* __restrict__ out) {
  __shared__ float red[2][64][2];  // [metric][row-in-block][col-half]

  const int tid  = threadIdx.x;
  const int lane = tid & 63;
  const int wv   = tid >> 6;
  const int l15  = lane & 15;
  const int quad = lane >> 4;
  const int rhalf = wv >> 1, chalf = wv & 1;
  const int rb = blockIdx.x * 64 + rhalf * 32;
  const int cb = chalf * 64;

  const bf16_t* xr0 = X  + (size_t)(rb + l15) * K + quad * 8;
  const bf16_t* wr0 = Wb + (size_t)(cb + l15) * K + quad * 8;

  f32x4 acc[2][4];  // [t: row tile][i: col tile]
  const f32x4 zero4 = {0.f, 0.f, 0.f, 0.f};
  for (int t = 0; t < 2; t++)
    for (int i = 0; i < 4; i++) acc[t][i] = zero4;

#pragma unroll 4
  for (int kk = 0; kk < K; kk += 32) {
    bf16x8 b0 = *(const bf16x8*)(xr0 + kk);
    bf16x8 b1 = *(const bf16x8*)(xr0 + 16 * K + kk);
#pragma unroll
    for (int i = 0; i < 4; i++) {
      bf16x8 a = *(const bf16x8*)(wr0 + (size_t)i * 16 * K + kk);
      acc[0][i] = mfma16(a, b0, acc[0][i]);
      acc[1][i] = mfma16(a, b1, acc[1][i]);
    }
  }

  // bias + residual; per-row sums
  f32x4 v[2][4];
  float s[2] = {0.f, 0.f}, sq[2] = {0.f, 0.f};
#pragma unroll
  for (int t = 0; t < 2; t++) {
    int row = rb + t * 16 + l15;
#pragma unroll
    for (int i = 0; i < 4; i++) {
      int c = cb + i * 16 + quad * 4;
      f32x4 vv = acc[t][i] + *(const f32x4*)(bias + c)
               + *(const f32x4*)(resid + (size_t)row * 128 + c);
      v[t][i] = vv;
      s[t]  += (vv[0] + vv[1]) + (vv[2] + vv[3]);
      sq[t] += (vv[0] * vv[0] + vv[1] * vv[1]) + (vv[2] * vv[2] + vv[3] * vv[3]);
    }
  }
#pragma unroll
  for (int t = 0; t < 2; t++) {
    s[t]  += __shfl_xor(s[t], 16, 64);  s[t]  += __shfl_xor(s[t], 32, 64);
    sq[t] += __shfl_xor(sq[t], 16, 64); sq[t] += __shfl_xor(sq[t], 32, 64);
    if (quad == 0) {
      red[0][rhalf * 32 + t * 16 + l15][chalf] = s[t];
      red[1][rhalf * 32 + t * 16 + l15][chalf] = sq[t];
    }
  }
  __syncthreads();
  float mean[2], rstd[2];
#pragma unroll
  for (int t = 0; t < 2; t++) {
    int rl = rhalf * 32 + t * 16 + l15;
    float S  = red[0][rl][0] + red[0][rl][1];
    float SQ = red[1][rl][0] + red[1][rl][1];
    mean[t] = S * (1.0f / 128.0f);
    rstd[t] = rsqrtf(SQ * (1.0f / 128.0f) - mean[t] * mean[t] + 1e-5f);
  }

  f32x4 g4[4], b4[4];
#pragma unroll
  for (int i = 0; i < 4; i++) {
    int c = cb + i * 16 + quad * 4;
    g4[i] = *(const f32x4*)(g1 + c);
    b4[i] = *(const f32x4*)(b1 + c);
  }

  if (MODE == 0) {
#pragma unroll
    for (int t = 0; t < 2; t++) {
      int row = rb + t * 16 + l15;
#pragma unroll
      for (int i = 0; i < 4; i++) {
        int c = cb + i * 16 + quad * 4;
        f32x4 y = (v[t][i] - mean[t]) * rstd[t] * g4[i] + b4[i];
        *(f32x4*)(xf_out + (size_t)row * 128 + c) = y;
        bf16x4 o = {(bf16_t)y[0], (bf16_t)y[1], (bf16_t)y[2], (bf16_t)y[3]};
        *(bf16x4*)(xb_out + (size_t)row * 128 + c) = o;
      }
    }
  } else if (MODE == 1) {
    // second LN with gathered class-table branch
    int lab[2];
    float s2v[2] = {0.f, 0.f}, sq2[2] = {0.f, 0.f};
#pragma unroll
    for (int t = 0; t < 2; t++) {
      lab[t] = labels[rb + t * 16 + l15];
#pragma unroll
      for (int i = 0; i < 4; i++) {
        int c = cb + i * 16 + quad * 4;
        f32x4 y = (v[t][i] - mean[t]) * rstd[t] * g4[i] + b4[i];
        y = y + *(const f32x4*)(tab + (size_t)lab[t] * 128 + c);
        v[t][i] = y;
        s2v[t] += (y[0] + y[1]) + (y[2] + y[3]);
        sq2[t] += (y[0] * y[0] + y[1] * y[1]) + (y[2] * y[2] + y[3] * y[3]);
      }
    }
    __syncthreads();  // all first-round red reads done
#pragma unroll
    for (int t = 0; t < 2; t++) {
      s2v[t] += __shfl_xor(s2v[t], 16, 64); s2v[t] += __shfl_xor(s2v[t], 32, 64);
      sq2[t] += __shfl_xor(sq2[t], 16, 64); sq2[t] += __shfl_xor(sq2[t], 32, 64);
      if (quad == 0) {
        red[0][rhalf * 32 + t * 16 + l15][chalf] = s2v[t];
        red[1][rhalf * 32 + t * 16 + l15][chalf] = sq2[t];
      }
    }
    __syncthreads();
#pragma unroll
    for (int t = 0; t < 2; t++) {
      int rl = rhalf * 32 + t * 16 + l15;
      float S  = red[0][rl][0] + red[0][rl][1];
      float SQ = red[1][rl][0] + red[1][rl][1];
      mean[t] = S * (1.0f / 128.0f);
      rstd[t] = rsqrtf(SQ * (1.0f / 128.0f) - mean[t] * mean[t] + 1e-5f);
    }
#pragma unroll
    for (int t = 0; t < 2; t++) {
      int row = rb + t * 16 + l15;
#pragma unroll
      for (int i = 0; i < 4; i++) {
        int c = cb + i * 16 + quad * 4;
        f32x4 y = (v[t][i] - mean[t]) * rstd[t] * (*(const f32x4*)(g2 + c))
                + *(const f32x4*)(b2 + c);
        *(f32x4*)(xf_out + (size_t)row * 128 + c) = y;
        bf16x4 o = {(bf16_t)y[0], (bf16_t)y[1], (bf16_t)y[2], (bf16_t)y[3]};
        *(bf16x4*)(xb_out + (size_t)row * 128 + c) = o;
      }
    }
  } else {  // MODE 2: LN -> fin dot -> sigmoid
    float dot[2] = {0.f, 0.f};
#pragma unroll
    for (int t = 0; t < 2; t++) {
#pragma unroll
      for (int i = 0; i < 4; i++) {
        int c = cb + i * 16 + quad * 4;
        f32x4 y = (v[t][i] - mean[t]) * rstd[t] * g4[i] + b4[i];
        f32x4 fw4 = *(const f32x4*)(fw + c);
        dot[t] += (y[0] * fw4[0] + y[1] * fw4[1]) + (y[2] * fw4[2] + y[3] * fw4[3]);
      }
    }
    __syncthreads();
#pragma unroll
    for (int t = 0; t < 2; t++) {
      dot[t] += __shfl_xor(dot[t], 16, 64); dot[t] += __shfl_xor(dot[t], 32, 64);
      if (quad == 0) red[0][rhalf * 32 + t * 16 + l15][chalf] = dot[t];
    }
    __syncthreads();
    if (chalf == 0 && quad == 0) {
      float fbv = fb[0];
#pragma unroll
      for (int t = 0; t < 2; t++) {
        int rl = rhalf * 32 + t * 16 + l15;
        float logit = red[0][rl][0] + red[0][rl][1] + fbv;
        out[blockIdx.x * 64 + rl] = 1.0f / (1.0f + expf(-logit));
      }
    }
  }
}

// ----------------------------------------- flash-decoding attention partial
// One wave = (head h, 32-query tile qt, 512-key split ks); 4096 wave-tasks.
// Block's 4 waves share (h,ks); K and V^T staged chunk-wise (128 keys) into
// LDS with coalesced 16B/thread copies, fragments via ds_read_b128.
// m=0 softmax (scores tiny). S^T order (mfma16(kf,qf)) -> b64 P-park.
__global__ __launch_bounds__(256, 4) void k_attn(const bf16_t* __restrict__ qkv,
                                                 const bf16_t* __restrict__ vT,
                                                 bf16_t* __restrict__ opart,
                                                 float* __restrict__ lpart) {
  __shared__ bf16_t kbuf[128][36];     // [key-in-chunk][dim] (+4 pad)
  __shared__ bf16_t vbuf[32][136];     // [dim][key-in-chunk] (+8 pad)
  __shared__ bf16_t pt[4][2][16][72];  // per-wave P park (64-key half)

  const int tid  = threadIdx.x;
  const int lane = tid & 63;
  const int wv   = tid >> 6;
  const int l15  = lane & 15;
  const int quad = lane >> 4;
  const int blk  = blockIdx.x;           // 0..1023
  const int h    = blk & 3;
  const int ks   = (blk >> 2) & 7;
  const int qt   = (blk >> 5) * 4 + wv;  // 0..127
  const int q0   = qt * 32;
  const int kb   = ks * 512;
  const int task = (qt * 8 + ks) * 4 + h;

  // Q frags (B-operand layout: query at l15, d at quad*8+j), prescaled
  bf16x8 qfA, qfB;
  {
    bf16x8 ra = *(const bf16x8*)(qkv + (size_t)(q0 + l15) * 384 + h * 32 + quad * 8);
    bf16x8 rb = *(const bf16x8*)(qkv + (size_t)(q0 + 16 + l15) * 384 + h * 32 + quad * 8);
#pragma unroll
    for (int j = 0; j < 8; j++) {
      qfA[j] = (bf16_t)((float)ra[j] * 0.17677669529663687f);
      qfB[j] = (bf16_t)((float)rb[j] * 0.17677669529663687f);
    }
  }

  const f32x4 zero4 = {0.f, 0.f, 0.f, 0.f};
  f32x4 oA0 = zero4, oA1 = zero4, oB0 = zero4, oB1 = zero4;
  float laccA = 0.f, laccB = 0.f;

  for (int kk = 0; kk < 512; kk += 128) {
    __syncthreads();  // protect kbuf/vbuf from previous chunk's readers
    // ---- stage K chunk: 128 rows x 32 dims (64 B/row, 4 x 16B threads/row)
#pragma unroll
    for (int rep = 0; rep < 2; rep++) {
      int idx = rep * 256 + tid;           // 0..511
      int row = idx >> 2, seg = idx & 3;
      bf16x8 t8 = *(const bf16x8*)(qkv + (size_t)(kb + kk + row) * 384
                                   + 128 + h * 32 + seg * 8);
      *(bf16x8*)&kbuf[row][seg * 8] = t8;
      // ---- stage V^T chunk: 32 dims x 128 keys (256 B/row, 16 x 16B/row)
      int dim = idx >> 4, vseg = idx & 15;
      bf16x8 v8 = *(const bf16x8*)(vT + (size_t)(h * 32 + dim) * 4096
                                   + kb + kk + vseg * 8);
      *(bf16x8*)&vbuf[dim][vseg * 8] = v8;
    }
    __syncthreads();

    // ---- two 64-key halves
#pragma unroll
    for (int half = 0; half < 2; half++) {
      const int ko = half * 64;
      bf16x8 kf0 = *(const bf16x8*)&kbuf[ko + l15][quad * 8];
      bf16x8 kf1 = *(const bf16x8*)&kbuf[ko + 16 + l15][quad * 8];
      bf16x8 kf2 = *(const bf16x8*)&kbuf[ko + 32 + l15][quad * 8];
      bf16x8 kf3 = *(const bf16x8*)&kbuf[ko + 48 + l15][quad * 8];

      f32x4 sA[4], sB[4];
      sA[0] = mfma16(kf0, qfA, zero4);
      sA[1] = mfma16(kf1, qfA, zero4);
      sA[2] = mfma16(kf2, qfA, zero4);
      sA[3] = mfma16(kf3, qfA, zero4);
      sB[0] = mfma16(kf0, qfB, zero4);
      sB[1] = mfma16(kf1, qfB, zero4);
      sB[2] = mfma16(kf2, qfB, zero4);
      sB[3] = mfma16(kf3, qfB, zero4);

#pragma unroll
      for (int t = 0; t < 4; t++) {
        float a0 = __expf(sA[t][0]), a1 = __expf(sA[t][1]);
        float a2 = __expf(sA[t][2]), a3 = __expf(sA[t][3]);
        laccA += (a0 + a1) + (a2 + a3);
        bf16x4 pa = {(bf16_t)a0, (bf16_t)a1, (bf16_t)a2, (bf16_t)a3};
        *(bf16x4*)&pt[wv][0][l15][t * 16 + quad * 4] = pa;
        float b0 = __expf(sB[t][0]), b1 = __expf(sB[t][1]);
        float b2 = __expf(sB[t][2]), b3 = __expf(sB[t][3]);
        laccB += (b0 + b1) + (b2 + b3);
        bf16x4 pb = {(bf16_t)b0, (bf16_t)b1, (bf16_t)b2, (bf16_t)b3};
        *(bf16x4*)&pt[wv][1][l15][t * 16 + quad * 4] = pb;
      }

      bf16x8 pA0 = *(const bf16x8*)&pt[wv][0][l15][quad * 8];
      bf16x8 pA1 = *(const bf16x8*)&pt[wv][0][l15][32 + quad * 8];
      bf16x8 pB0 = *(const bf16x8*)&pt[wv][1][l15][quad * 8];
      bf16x8 pB1 = *(const bf16x8*)&pt[wv][1][l15][32 + quad * 8];

      bf16x8 v00 = *(const bf16x8*)&vbuf[l15][ko + quad * 8];
      bf16x8 v01 = *(const bf16x8*)&vbuf[16 + l15][ko + quad * 8];
      bf16x8 v10 = *(const bf16x8*)&vbuf[l15][ko + 32 + quad * 8];
      bf16x8 v11 = *(const bf16x8*)&vbuf[16 + l15][ko + 32 + quad * 8];

      oA0 = mfma16(pA0, v00, oA0);
      oA0 = mfma16(pA1, v10, oA0);
      oA1 = mfma16(pA0, v01, oA1);
      oA1 = mfma16(pA1, v11, oA1);
      oB0 = mfma16(pB0, v00, oB0);
      oB0 = mfma16(pB1, v10, oB0);
      oB1 = mfma16(pB0, v01, oB1);
      oB1 = mfma16(pB1, v11, oB1);
    }
  }

  // l: sum the 4 quad-partials for each query lane
  laccA += __shfl_xor(laccA, 16, 64); laccA += __shfl_xor(laccA, 32, 64);
  laccB += __shfl_xor(laccB, 16, 64); laccB += __shfl_xor(laccB, 32, 64);
  if (quad == 0) {
    lpart[task * 32 + l15]      = laccA;
    lpart[task * 32 + 16 + l15] = laccB;
  }

  size_t ob = (size_t)task * 1024;  // [32 queries][32 dims]
#pragma unroll
  for (int r = 0; r < 4; r++) {
    int qa = quad * 4 + r;
    opart[ob + qa * 32 + l15]             = (bf16_t)oA0[r];
    opart[ob + qa * 32 + 16 + l15]        = (bf16_t)oA1[r];
    opart[ob + (16 + qa) * 32 + l15]      = (bf16_t)oB0[r];
    opart[ob + (16 + qa) * 32 + 16 + l15] = (bf16_t)oB1[r];
  }
}

// ------------------------------------------------ combine ksplit partials
__global__ __launch_bounds__(256) void k_attn_fin(const bf16_t* __restrict__ opart,
                                                  const float* __restrict__ lpart,
                                                  bf16_t* __restrict__ attnb) {
  int idx = blockIdx.x * 256 + threadIdx.x;  // ((h*4096+q)*32+d), < 524288
  int d  = idx & 31;
  int q  = (idx >> 5) & 4095;
  int h  = idx >> 17;
  int qt = q >> 5, ql = q & 31;
  float O = 0.f, L = 0.f;
#pragma unroll
  for (int ks = 0; ks < 8; ks++) {
    int t = (qt * 8 + ks) * 4 + h;
    O += (float)opart[(size_t)t * 1024 + ql * 32 + d];
    L += lpart[t * 32 + ql];
  }
  attnb[(size_t)q * 128 + h * 32 + d] = (bf16_t)(O / L);
}

// --------------------------------------------------------------------------
extern "C" void kernel_launch(void* const* d_in, const int* in_sizes, int n_in,
                              void* d_out, int out_size, void* d_ws, size_t ws_size,
                              hipStream_t stream) {
  const float* coords  = (const float*)d_in[0];
  const int*   labels  = (const int*)d_in[1];
  const float* ce_w    = (const float*)d_in[2];
  const float* ce_b    = (const float*)d_in[3];
  const float* emb     = (const float*)d_in[4];
  const float* sa_in_w = (const float*)d_in[5];
  const float* sa_in_b = (const float*)d_in[6];
  const float* sa_out_w= (const float*)d_in[7];
  const float* sa_out_b= (const float*)d_in[8];
  const float* n1_g    = (const float*)d_in[9];
  const float* n1_b    = (const float*)d_in[10];
  const float* m1_w1   = (const float*)d_in[11];
  const float* m1_b1   = (const float*)d_in[12];
  const float* m1_w2   = (const float*)d_in[13];
  const float* m1_b2   = (const float*)d_in[14];
  const float* n2_g    = (const float*)d_in[15];
  const float* n2_b    = (const float*)d_in[16];
  const float* ca_in_w = (const float*)d_in[17];
  const float* ca_in_b = (const float*)d_in[18];
  const float* ca_out_w= (const float*)d_in[19];
  const float* ca_out_b= (const float*)d_in[20];
  const float* n3_g    = (const float*)d_in[21];
  const float* n3_b    = (const float*)d_in[22];
  const float* m2_w1   = (const float*)d_in[23];
  const float* m2_b1   = (const float*)d_in[24];
  const float* m2_w2   = (const float*)d_in[25];
  const float* m2_b2   = (const float*)d_in[26];
  const float* n4_g    = (const float*)d_in[27];
  const float* n4_b    = (const float*)d_in[28];
  const float* fin_w   = (const float*)d_in[29];
  const float* fin_b   = (const float*)d_in[30];
  float* outp = (float*)d_out;

  // workspace layout (bytes, 16B-aligned); total 17,965,056 B
  char* w = (char*)d_ws;
  float*  xf    = (float*)(w);
  float*  tab   = (float*)(w + 2097152);
  bf16_t* wsb   = (bf16_t*)(w + 2105344);
  bf16_t* xb    = (bf16_t*)(w + 2760704);
  bf16_t* attnb = (bf16_t*)(w + 3809280);
  bf16_t* qkvb  = (bf16_t*)(w + 4857856);
  bf16_t* vT    = (bf16_t*)(w + 8003584);
  bf16_t* opart = (bf16_t*)(w + 9052160);   // 8 MB: 4096 tasks x 32q x 32d
  bf16_t* h1b   = (bf16_t*)(w + 9052160);   // alias (opart dead after fin)
  float*  lpart = (float*)(w + 17440768);   // 512 KB: 4096 x 32

  bf16_t* w_sain  = wsb;
  bf16_t* w_saout = wsb + 49152;
  bf16_t* w_m1w1  = wsb + 65536;
  bf16_t* w_m1w2  = wsb + 131072;
  bf16_t* w_m2w1  = wsb + 196608;
  bf16_t* w_m2w2  = wsb + 262144;

  // embed + weight cvt + ca table (independent, one kernel)
  k_init<<<2369, 256, 0, stream>>>(coords, ce_w, ce_b, xf, xb,
                                   sa_in_w, sa_out_w, m1_w1, m1_w2, m2_w1, m2_w2,
                                   wsb, emb, ca_in_w + 256 * 128, ca_in_b + 256,
                                   ca_out_w, ca_out_b, tab);
  // qkv projection (+ transposed V)
  k_gemm<128, EPI_BF16><<<dim3(64, 6), 256, 0, stream>>>(xb, w_sain, sa_in_b,
                                                         qkvb, vT, 384);
  // self-attention: ksplit=8 partials, then combine
  k_attn<<<1024, 256, 0, stream>>>(qkvb, vT, opart, lpart);
  k_attn_fin<<<2048, 256, 0, stream>>>(opart, lpart, attnb);
  // out-proj + residual + ln1
  k_gemmln<128, 0><<<64, 256, 0, stream>>>(attnb, w_saout, sa_out_b, xf,
                                           n1_g, n1_b, nullptr, nullptr,
                                           nullptr, nullptr, nullptr, nullptr,
                                           xf, xb, nullptr);
  // mlp1 up (GELU)
  k_gemm<128, EPI_GELU_BF16><<<dim3(64, 8), 256, 0, stream>>>(xb, w_m1w1, m1_b1,
                                                              h1b, nullptr, 512);
  // mlp1 down + ln2 + (ca gather) + ln3
  k_gemmln<512, 1><<<64, 256, 0, stream>>>(h1b, w_m1w2, m1_b2, xf,
                                           n2_g, n2_b, labels, tab,
                                           n3_g, n3_b, nullptr, nullptr,
                                           xf, xb, nullptr);
  // mlp2 up (GELU)
  k_gemm<128, EPI_GELU_BF16><<<dim3(64, 8), 256, 0, stream>>>(xb, w_m2w1, m2_b1,
                                                              h1b, nullptr, 512);
  // mlp2 down + ln4 + fin + sigmoid
  k_gemmln<512, 2><<<64, 256, 0, stream>>>(h1b, w_m2w2, m2_b2, xf,
                                           n4_g, n4_b, nullptr, nullptr,
                                           nullptr, nullptr, fin_w, fin_b,
                                           nullptr, nullptr, outp);

  (void)in_sizes; (void)n_in; (void)out_size; (void)ws_size;
}